// Round 4
// baseline (580.764 us; speedup 1.0000x reference)
//
#include <hip/hip_runtime.h>
#include <cstdint>
#include <cstddef>

#define N_NODES 100000
#define E_EDGES 1600000
#define E_TOT   1700000
#define HEADS   8
#define C1      8
#define HC1     64
#define NCLS    3
#define HC2     24
#define IN_CH   500
#define NEG     0.2f

#define SEG     2048
#define NSEG    49      /* ceil(100000/2048) */

typedef __attribute__((ext_vector_type(8))) short bf16x8;
typedef __attribute__((ext_vector_type(4))) float f32x4;

__device__ __forceinline__ unsigned short f2bf(float f) {
  unsigned u = __float_as_uint(f);
  u += 0x7FFFu + ((u >> 16) & 1u);
  return (unsigned short)(u >> 16);
}
__device__ __forceinline__ float bfhi(unsigned short h) {
  return __uint_as_float(((unsigned)h) << 16);
}

// ---------------- edge dtype detection (int32 vs int64 edge_index) -----------
__global__ void k_detect(const int* __restrict__ ei, int* __restrict__ flag) {
  int i = blockIdx.x * blockDim.x + threadIdx.x;   // 4096 threads
  bool nz = ei[2 * i + 1] != 0;
  if (__ballot(nz)) {
    if ((threadIdx.x & 63) == 0) atomicOr(flag, 1);
  }
}

__device__ __forceinline__ int edge_at(const int* __restrict__ ei, int idx, int mode) {
  return mode ? ei[idx] : ei[2 * idx];   // int64: low word
}

// ---------------- CSR build --------------------------------------------------
__global__ void k_hist(const int* __restrict__ ei, const int* __restrict__ flag,
                       int* __restrict__ deg) {
  int e = blockIdx.x * blockDim.x + threadIdx.x;
  if (e >= E_TOT) return;
  int mode = *flag;
  int d = (e < E_EDGES) ? edge_at(ei, E_EDGES + e, mode) : (e - E_EDGES);
  atomicAdd(&deg[d], 1);
}

__global__ void k_seg_sum(const int* __restrict__ deg, int* __restrict__ segsum) {
  __shared__ int sh[256];
  int tid = threadIdx.x;
  int base = blockIdx.x * SEG;
  int sum = 0;
#pragma unroll
  for (int j = 0; j < 8; ++j) {
    int idx = base + j * 256 + tid;
    if (idx < N_NODES) sum += deg[idx];
  }
  sh[tid] = sum; __syncthreads();
  for (int off = 128; off > 0; off >>= 1) {
    if (tid < off) sh[tid] += sh[tid + off];
    __syncthreads();
  }
  if (tid == 0) segsum[blockIdx.x] = sh[0];
}

__global__ void k_scan_small(const int* __restrict__ segsum, int* __restrict__ segoff,
                             int* __restrict__ rowptr) {
  if (threadIdx.x == 0 && blockIdx.x == 0) {
    int run = 0;
    for (int s = 0; s < NSEG; ++s) { int t = segsum[s]; segoff[s] = run; run += t; }
    rowptr[N_NODES] = run;   // == E_TOT
  }
}

__global__ void k_seg_scan(const int* __restrict__ deg, const int* __restrict__ segoff,
                           int* __restrict__ rowptr) {
  __shared__ int sh[256];
  int tid = threadIdx.x;
  int idx0 = blockIdx.x * SEG + tid * 8;
  int v[8]; int tsum = 0;
#pragma unroll
  for (int j = 0; j < 8; ++j) {
    int idx = idx0 + j;
    v[j] = (idx < N_NODES) ? deg[idx] : 0;
    tsum += v[j];
  }
  sh[tid] = tsum; __syncthreads();
  for (int off = 1; off < 256; off <<= 1) {
    int add = (tid >= off) ? sh[tid - off] : 0;
    __syncthreads();
    sh[tid] += add;
    __syncthreads();
  }
  int run = segoff[blockIdx.x] + sh[tid] - tsum;   // exclusive prefix
#pragma unroll
  for (int j = 0; j < 8; ++j) {
    int idx = idx0 + j;
    if (idx < N_NODES) rowptr[idx] = run;
    run += v[j];
  }
}

__global__ void k_scatter(const int* __restrict__ ei, const int* __restrict__ flag,
                          const int* __restrict__ rowptr, int* __restrict__ cnt,
                          int* __restrict__ esrc) {
  int e = blockIdx.x * blockDim.x + threadIdx.x;
  if (e >= E_TOT) return;
  int mode = *flag;
  int s, d;
  if (e < E_EDGES) { s = edge_at(ei, e, mode); d = edge_at(ei, E_EDGES + e, mode); }
  else             { s = e - E_EDGES; d = s; }
  int pos = rowptr[d] + atomicAdd(&cnt[d], 1);
  esrc[pos] = s;
}

// ---------------- W1 pre-convert: fp32 [500][128] -> bf16 hi/lo, [N=128][K=512]
__global__ void k_wconv(const float* __restrict__ W1l, const float* __restrict__ W1r,
                        unsigned short* __restrict__ WtHi, unsigned short* __restrict__ WtLo) {
  int t = blockIdx.x * 256 + threadIdx.x;   // 65536 = 128*512
  int n = t >> 9, k = t & 511;
  float v = 0.f;
  if (k < IN_CH) v = (n < HC1) ? W1l[k * HC1 + n] : W1r[k * HC1 + (n - HC1)];
  unsigned short h = f2bf(v);
  unsigned short l = f2bf(v - bfhi(h));
  WtHi[n * 512 + k] = h;
  WtLo[n * 512 + k] = l;
}

// ---------------- GEMM1 via split-bf16 MFMA, M-tile=16, high TLP -------------
// Block = 4 waves over ONE 16-row M-tile; wave w owns output cols
// [w*32, w*32+32). A (16x64 fp32 -> bf16 hi/lo) staged in 4KB swizzled LDS;
// B fragments read straight from the L2-hot 256KB Wt tables. Grid = 6250
// blocks (~24/CU) so many independent K-step pipelines overlap the stalls.
#define LDS_AHI 0
#define LDS_ALO 2048

__global__ __launch_bounds__(256, 6) void k_gemm1(const float* __restrict__ x,
    const unsigned short* __restrict__ WtHi, const unsigned short* __restrict__ WtLo,
    float* __restrict__ xl, float* __restrict__ xr) {
  __shared__ char lds[4096];
  const int tid  = threadIdx.x;
  const int bm0  = blockIdx.x * 16;          // N_NODES % 16 == 0
  const int lane = tid & 63, wid = tid >> 6;
  const int lrow = lane & 15, kg = lane >> 4;

  f32x4 acc[2];
  acc[0] = (f32x4){0.f, 0.f, 0.f, 0.f};
  acc[1] = (f32x4){0.f, 0.f, 0.f, 0.f};

  const int r  = tid >> 4;        // 0..15 (row in M-tile)
  const int c4 = tid & 15;        // 0..15 (float4 within 64-k chunk)
  float4 av;
  auto loadA = [&](int ks) {
    int k = ks * 64 + c4 * 4;
    av = make_float4(0.f, 0.f, 0.f, 0.f);
    if (k < IN_CH)                 // IN_CH % 4 == 0 -> full float4 ok
      av = *(const float4*)&x[(size_t)(bm0 + r) * IN_CH + k];
  };

  loadA(0);
  for (int ks = 0; ks < 8; ++ks) {
    if (ks) __syncthreads();
    ushort4 h, l;
    h.x = f2bf(av.x); l.x = f2bf(av.x - bfhi(h.x));
    h.y = f2bf(av.y); l.y = f2bf(av.y - bfhi(h.y));
    h.z = f2bf(av.z); l.z = f2bf(av.z - bfhi(h.z));
    h.w = f2bf(av.w); l.w = f2bf(av.w - bfhi(h.w));
    int boff = (r * 128 + c4 * 8) ^ ((r & 7) << 4);
    *(ushort4*)(lds + LDS_AHI + boff) = h;
    *(ushort4*)(lds + LDS_ALO + boff) = l;
    if (ks < 7) loadA(ks + 1);               // issue next-step load now
    __syncthreads();
#pragma unroll
    for (int kk = 0; kk < 2; ++kk) {
      const int kelem = ks * 64 + kk * 32 + kg * 8;
      bf16x8 bh[2], bl[2];
#pragma unroll
      for (int n = 0; n < 2; ++n) {
        int row = wid * 32 + n * 16 + lrow;
        bh[n] = *(const bf16x8*)&WtHi[row * 512 + kelem];
        bl[n] = *(const bf16x8*)&WtLo[row * 512 + kelem];
      }
      int aoff = (lrow * 128 + kk * 64 + kg * 16) ^ ((lrow & 7) << 4);
      bf16x8 ah = *(const bf16x8*)(lds + LDS_AHI + aoff);
      bf16x8 al = *(const bf16x8*)(lds + LDS_ALO + aoff);
#pragma unroll
      for (int n = 0; n < 2; ++n) {
        acc[n] = __builtin_amdgcn_mfma_f32_16x16x32_bf16(ah, bh[n], acc[n], 0, 0, 0);
        acc[n] = __builtin_amdgcn_mfma_f32_16x16x32_bf16(ah, bl[n], acc[n], 0, 0, 0);
        acc[n] = __builtin_amdgcn_mfma_f32_16x16x32_bf16(al, bh[n], acc[n], 0, 0, 0);
      }
    }
  }
  // store: col = wid*32 + n*16 + lrow, row = kg*4 + j
  float* dst = (wid < 2) ? xl : xr;
#pragma unroll
  for (int n = 0; n < 2; ++n) {
    int cc = (wid * 32 + n * 16 + lrow) & 63;
#pragma unroll
    for (int j = 0; j < 4; ++j) {
      int grow = bm0 + kg * 4 + j;
      dst[(size_t)grow * HC1 + cc] = acc[n][j];
    }
  }
}

// ---------------- layer-1 edge pass: wave/node, 8-way edge-parallel ----------
// lane = h*8+e: head h, edge slot e. 8 edges in flight per head. Online
// softmax state (m,s,acc[8]) per lane, merged across e via shfl_xor(1,2,4).
__global__ __launch_bounds__(256) void k_edge1(const float* __restrict__ xl1,
    const float* __restrict__ xr1, const float* __restrict__ att1,
    const float* __restrict__ b1, const int* __restrict__ rowptr,
    const int* __restrict__ esrc, float* __restrict__ hbuf) {
  int node = blockIdx.x * 4 + (threadIdx.x >> 6);   // grid exact: N/4 blocks
  int lane = threadIdx.x & 63;
  int h = lane >> 3, e = lane & 7;

  const float4* xrp = (const float4*)(xr1 + (size_t)node * HC1 + h * C1);
  float4 xa = xrp[0], xb = xrp[1];
  float xrv[8] = {xa.x, xa.y, xa.z, xa.w, xb.x, xb.y, xb.z, xb.w};
  const float4* ap = (const float4*)(att1 + h * C1);
  float4 aa = ap[0], ab = ap[1];
  float av[8] = {aa.x, aa.y, aa.z, aa.w, ab.x, ab.y, ab.z, ab.w};

  float m = -INFINITY, s = 0.f;
  float acc[8];
#pragma unroll
  for (int c = 0; c < 8; ++c) acc[c] = 0.f;

  int beg = rowptr[node], end = rowptr[node + 1];
  for (int i = beg + e; i < end; i += 8) {
    int sn = esrc[i];
    const float4* xlp = (const float4*)(xl1 + (size_t)sn * HC1 + h * C1);
    float4 la = xlp[0], lb = xlp[1];
    float xlv[8] = {la.x, la.y, la.z, la.w, lb.x, lb.y, lb.z, lb.w};
    float logit = 0.f;
#pragma unroll
    for (int c = 0; c < 8; ++c) {
      float u = xlv[c] + xrv[c];
      u = (u > 0.f) ? u : NEG * u;
      logit = fmaf(u, av[c], logit);
    }
    float mn = fmaxf(m, logit);
    float so = __expf(m - mn);       // first edge: m=-inf, mn finite -> 0
    float p  = __expf(logit - mn);
    s = s * so + p;
#pragma unroll
    for (int c = 0; c < 8; ++c) acc[c] = fmaf(acc[c], so, p * xlv[c]);
    m = mn;
  }
  // merge the 8 e-lane states within each head (lanes differ in bits 0..2)
#pragma unroll
  for (int off = 1; off < 8; off <<= 1) {
    float mo = __shfl_xor(m, off);
    float so_ = __shfl_xor(s, off);
    float mn = fmaxf(m, mo);
    float fa = (m  == -INFINITY) ? 0.f : __expf(m  - mn);
    float fb = (mo == -INFINITY) ? 0.f : __expf(mo - mn);
    s = s * fa + so_ * fb;
#pragma unroll
    for (int c = 0; c < 8; ++c) {
      float ao = __shfl_xor(acc[c], off);
      acc[c] = acc[c] * fa + ao * fb;
    }
    m = mn;
  }
  if (e == 0) {
    float inv = 1.f / s;
    float o[8];
#pragma unroll
    for (int c = 0; c < 8; ++c) {
      float v = fmaf(acc[c], inv, b1[h * C1 + c]);
      o[c] = (v > 0.f) ? v : expm1f(v);    // ELU
    }
    float4* hp = (float4*)(hbuf + (size_t)node * HC1 + h * C1);
    hp[0] = make_float4(o[0], o[1], o[2], o[3]);
    hp[1] = make_float4(o[4], o[5], o[6], o[7]);
  }
}

// ---------------- GEMM2: xl2 = h@W2l, xr2 = h@W2r  (64 -> 24 each) -----------
__global__ __launch_bounds__(256) void k_gemm2(const float* __restrict__ hbuf,
    const float* __restrict__ W2l, const float* __restrict__ W2r,
    float* __restrict__ xl2, float* __restrict__ xr2) {
  __shared__ float w[64][48];
  int tid = threadIdx.x;
  for (int i = tid; i < 64 * 48; i += 256) {
    int k = i / 48, j = i - k * 48;
    w[k][j] = (j < HC2) ? W2l[k * HC2 + j] : W2r[k * HC2 + (j - HC2)];
  }
  __syncthreads();
  int node = blockIdx.x * 256 + tid;
  if (node >= N_NODES) return;
  float acc[48];
#pragma unroll
  for (int j = 0; j < 48; ++j) acc[j] = 0.f;
  const float4* hp = (const float4*)(hbuf + (size_t)node * HC1);
  for (int k0 = 0; k0 < 64; k0 += 16) {
    float rv[16];
#pragma unroll
    for (int q = 0; q < 4; ++q) {
      float4 r4 = hp[k0 / 4 + q];
      rv[q*4+0] = r4.x; rv[q*4+1] = r4.y; rv[q*4+2] = r4.z; rv[q*4+3] = r4.w;
    }
#pragma unroll
    for (int kk = 0; kk < 16; ++kk) {
      float hv = rv[kk];
      const float4* wrow = (const float4*)&w[k0 + kk][0];
#pragma unroll
      for (int j4 = 0; j4 < 12; ++j4) {
        float4 wv = wrow[j4];
        acc[j4*4+0] = fmaf(hv, wv.x, acc[j4*4+0]);
        acc[j4*4+1] = fmaf(hv, wv.y, acc[j4*4+1]);
        acc[j4*4+2] = fmaf(hv, wv.z, acc[j4*4+2]);
        acc[j4*4+3] = fmaf(hv, wv.w, acc[j4*4+3]);
      }
    }
  }
  float4* lp = (float4*)(xl2 + (size_t)node * HC2);
  float4* rp = (float4*)(xr2 + (size_t)node * HC2);
#pragma unroll
  for (int j4 = 0; j4 < 6; ++j4) {
    lp[j4] = make_float4(acc[j4*4+0], acc[j4*4+1], acc[j4*4+2], acc[j4*4+3]);
    rp[j4] = make_float4(acc[24+j4*4+0], acc[24+j4*4+1], acc[24+j4*4+2], acc[24+j4*4+3]);
  }
}

// ---------------- layer-2 edge pass: wave/node + head-mean + softmax ---------
__global__ __launch_bounds__(256) void k_edge2(const float* __restrict__ xl2,
    const float* __restrict__ xr2, const float* __restrict__ att2,
    const float* __restrict__ b2, const int* __restrict__ rowptr,
    const int* __restrict__ esrc, float* __restrict__ out) {
  int node = blockIdx.x * 4 + (threadIdx.x >> 6);   // grid exact: N/4 blocks
  int lane = threadIdx.x & 63;
  int h = lane >> 3, e = lane & 7;

  float xrv[3], av[3];
#pragma unroll
  for (int c = 0; c < 3; ++c) {
    xrv[c] = xr2[(size_t)node * HC2 + h * NCLS + c];
    av[c]  = att2[h * NCLS + c];
  }
  float m = -INFINITY, s = 0.f;
  float acc[3] = {0.f, 0.f, 0.f};

  int beg = rowptr[node], end = rowptr[node + 1];
  for (int i = beg + e; i < end; i += 8) {
    int sn = esrc[i];
    float xlv[3];
#pragma unroll
    for (int c = 0; c < 3; ++c) xlv[c] = xl2[(size_t)sn * HC2 + h * NCLS + c];
    float logit = 0.f;
#pragma unroll
    for (int c = 0; c < 3; ++c) {
      float u = xlv[c] + xrv[c];
      u = (u > 0.f) ? u : NEG * u;
      logit = fmaf(u, av[c], logit);
    }
    float mn = fmaxf(m, logit);
    float so = __expf(m - mn);
    float p  = __expf(logit - mn);
    s = s * so + p;
#pragma unroll
    for (int c = 0; c < 3; ++c) acc[c] = fmaf(acc[c], so, p * xlv[c]);
    m = mn;
  }
  // merge across e-lanes (bits 0..2)
#pragma unroll
  for (int off = 1; off < 8; off <<= 1) {
    float mo = __shfl_xor(m, off);
    float so_ = __shfl_xor(s, off);
    float mn = fmaxf(m, mo);
    float fa = (m  == -INFINITY) ? 0.f : __expf(m  - mn);
    float fb = (mo == -INFINITY) ? 0.f : __expf(mo - mn);
    s = s * fa + so_ * fb;
#pragma unroll
    for (int c = 0; c < 3; ++c) {
      float ao = __shfl_xor(acc[c], off);
      acc[c] = acc[c] * fa + ao * fb;
    }
    m = mn;
  }
  float inv = 1.f / s;
  float o[3];
#pragma unroll
  for (int c = 0; c < 3; ++c) o[c] = acc[c] * inv;
  // mean over heads: sum across h-lanes (bits 3..5)
#pragma unroll
  for (int off = 8; off < 64; off <<= 1) {
#pragma unroll
    for (int c = 0; c < 3; ++c) o[c] += __shfl_xor(o[c], off);
  }
  if (lane == 0) {
    float z[3];
#pragma unroll
    for (int c = 0; c < 3; ++c) z[c] = o[c] * 0.125f + b2[c];
    float mx = fmaxf(fmaxf(z[0], z[1]), z[2]);
    float e0 = __expf(z[0] - mx), e1 = __expf(z[1] - mx), e2 = __expf(z[2] - mx);
    float sum = e0 + e1 + e2;
    out[(size_t)node * NCLS + 0] = e0 / sum;
    out[(size_t)node * NCLS + 1] = e1 / sum;
    out[(size_t)node * NCLS + 2] = e2 / sum;
  }
}

// ---------------- launch -----------------------------------------------------
extern "C" void kernel_launch(void* const* d_in, const int* in_sizes, int n_in,
                              void* d_out, int out_size, void* d_ws, size_t ws_size,
                              hipStream_t stream) {
  (void)in_sizes; (void)n_in; (void)out_size; (void)ws_size;
  const float* x    = (const float*)d_in[0];
  const int*   ei   = (const int*)d_in[1];
  const float* W1l  = (const float*)d_in[2];
  const float* W1r  = (const float*)d_in[3];
  const float* att1 = (const float*)d_in[4];
  const float* b1   = (const float*)d_in[5];
  const float* W2l  = (const float*)d_in[6];
  const float* W2r  = (const float*)d_in[7];
  const float* att2 = (const float*)d_in[8];
  const float* b2   = (const float*)d_in[9];
  float* out = (float*)d_out;

  char* w = (char*)d_ws;
  float* xl1  = (float*)(w);                 // 25.6 MB
  float* xr1  = (float*)(w + 25600000);      // 25.6 MB
  float* hbuf = (float*)(w + 51200000);      // 25.6 MB (Wt tables live here pre-edge1)
  float* xl2  = (float*)(w);                 // overlays xl1 (dead after edge1)
  float* xr2  = (float*)(w + 9600000);       // inside old xl1 region
  unsigned short* WtHi = (unsigned short*)(w + 51200000);           // 128 KB
  unsigned short* WtLo = (unsigned short*)(w + 51200000 + 131072);  // 128 KB
  char* ip = w + 76800000;
  int* deg    = (int*)(ip);                  // 400000 B
  int* cnt    = (int*)(ip + 400000);         // 400000 B
  int* rowptr = (int*)(ip + 800000);         // 400004 B
  int* segsum = (int*)(ip + 1200256);
  int* segoff = (int*)(ip + 1200512);
  int* flag   = (int*)(ip + 1200768);
  int* esrc   = (int*)(ip + 1201024);        // 6.8 MB  -> total ~84.8 MB

  hipMemsetAsync(deg, 0, 800000, stream);    // deg + cnt (contiguous)
  hipMemsetAsync(flag, 0, 4, stream);

  k_detect   <<<16, 256, 0, stream>>>(ei, flag);
  k_wconv    <<<256, 256, 0, stream>>>(W1l, W1r, WtHi, WtLo);
  k_hist     <<<(E_TOT + 255) / 256, 256, 0, stream>>>(ei, flag, deg);
  k_seg_sum  <<<NSEG, 256, 0, stream>>>(deg, segsum);
  k_scan_small<<<1, 64, 0, stream>>>(segsum, segoff, rowptr);
  k_seg_scan <<<NSEG, 256, 0, stream>>>(deg, segoff, rowptr);
  k_scatter  <<<(E_TOT + 255) / 256, 256, 0, stream>>>(ei, flag, rowptr, cnt, esrc);
  k_gemm1    <<<N_NODES / 16, 256, 0, stream>>>(x, WtHi, WtLo, xl1, xr1);
  k_edge1    <<<N_NODES / 4, 256, 0, stream>>>(xl1, xr1, att1, b1, rowptr, esrc, hbuf);
  k_gemm2    <<<(N_NODES + 255) / 256, 256, 0, stream>>>(hbuf, W2l, W2r, xl2, xr2);
  k_edge2    <<<N_NODES / 4, 256, 0, stream>>>(xl2, xr2, att2, b2, rowptr, esrc, out);
}

// Round 5
// 385.550 us; speedup vs baseline: 1.5063x; 1.5063x over previous
//
#include <hip/hip_runtime.h>
#include <cstdint>
#include <cstddef>

#define N_NODES 100000
#define E_EDGES 1600000
#define E_TOT   1700000
#define HEADS   8
#define C1      8
#define HC1     64
#define NCLS    3
#define HC2     24
#define IN_CH   500
#define NEG     0.2f

#define SEG     2048
#define NSEG    49      /* ceil(100000/2048) */

#define TILES   6250    /* 100000 / 16 */
#define NBLK    256

typedef __attribute__((ext_vector_type(8))) _Float16 f16x8;
typedef __attribute__((ext_vector_type(4))) _Float16 f16x4;
typedef __attribute__((ext_vector_type(4))) float f32x4;

// ---------------- edge dtype detection (int32 vs int64 edge_index) -----------
__global__ void k_detect(const int* __restrict__ ei, int* __restrict__ flag) {
  int i = blockIdx.x * blockDim.x + threadIdx.x;   // 4096 threads
  bool nz = ei[2 * i + 1] != 0;
  if (__ballot(nz)) {
    if ((threadIdx.x & 63) == 0) atomicOr(flag, 1);
  }
}

__device__ __forceinline__ int edge_at(const int* __restrict__ ei, int idx, int mode) {
  return mode ? ei[idx] : ei[2 * idx];   // int64: low word
}

// ---------------- CSR build --------------------------------------------------
__global__ void k_hist(const int* __restrict__ ei, const int* __restrict__ flag,
                       int* __restrict__ deg) {
  int e = blockIdx.x * blockDim.x + threadIdx.x;
  if (e >= E_TOT) return;
  int mode = *flag;
  int d = (e < E_EDGES) ? edge_at(ei, E_EDGES + e, mode) : (e - E_EDGES);
  atomicAdd(&deg[d], 1);
}

__global__ void k_seg_sum(const int* __restrict__ deg, int* __restrict__ segsum) {
  __shared__ int sh[256];
  int tid = threadIdx.x;
  int base = blockIdx.x * SEG;
  int sum = 0;
#pragma unroll
  for (int j = 0; j < 8; ++j) {
    int idx = base + j * 256 + tid;
    if (idx < N_NODES) sum += deg[idx];
  }
  sh[tid] = sum; __syncthreads();
  for (int off = 128; off > 0; off >>= 1) {
    if (tid < off) sh[tid] += sh[tid + off];
    __syncthreads();
  }
  if (tid == 0) segsum[blockIdx.x] = sh[0];
}

__global__ void k_scan_small(const int* __restrict__ segsum, int* __restrict__ segoff,
                             int* __restrict__ rowptr) {
  if (threadIdx.x == 0 && blockIdx.x == 0) {
    int run = 0;
    for (int s = 0; s < NSEG; ++s) { int t = segsum[s]; segoff[s] = run; run += t; }
    rowptr[N_NODES] = run;   // == E_TOT
  }
}

__global__ void k_seg_scan(const int* __restrict__ deg, const int* __restrict__ segoff,
                           int* __restrict__ rowptr) {
  __shared__ int sh[256];
  int tid = threadIdx.x;
  int idx0 = blockIdx.x * SEG + tid * 8;
  int v[8]; int tsum = 0;
#pragma unroll
  for (int j = 0; j < 8; ++j) {
    int idx = idx0 + j;
    v[j] = (idx < N_NODES) ? deg[idx] : 0;
    tsum += v[j];
  }
  sh[tid] = tsum; __syncthreads();
  for (int off = 1; off < 256; off <<= 1) {
    int add = (tid >= off) ? sh[tid - off] : 0;
    __syncthreads();
    sh[tid] += add;
    __syncthreads();
  }
  int run = segoff[blockIdx.x] + sh[tid] - tsum;   // exclusive prefix
#pragma unroll
  for (int j = 0; j < 8; ++j) {
    int idx = idx0 + j;
    if (idx < N_NODES) rowptr[idx] = run;
    run += v[j];
  }
}

__global__ void k_scatter(const int* __restrict__ ei, const int* __restrict__ flag,
                          const int* __restrict__ rowptr, int* __restrict__ cnt,
                          int* __restrict__ esrc) {
  int e = blockIdx.x * blockDim.x + threadIdx.x;
  if (e >= E_TOT) return;
  int mode = *flag;
  int s, d;
  if (e < E_EDGES) { s = edge_at(ei, e, mode); d = edge_at(ei, E_EDGES + e, mode); }
  else             { s = e - E_EDGES; d = s; }
  int pos = rowptr[d] + atomicAdd(&cnt[d], 1);
  esrc[pos] = s;
}

// ---------------- W1 pre-convert to fp16 LDS-image ---------------------------
// Image layout == desired LDS layout: [col 0..127][k 0..511] fp16, row stride
// 1024B, XOR-swizzled byte ^= (col&7)<<4, k>=500 zero-padded. 128KB.
__global__ void k_wconv(const float* __restrict__ W1l, const float* __restrict__ W1r,
                        _Float16* __restrict__ Wimg) {
  int t = blockIdx.x * 256 + threadIdx.x;   // 65536 = 128*512
  int col = t >> 9, k = t & 511;
  float v = 0.f;
  if (k < IN_CH) v = (col < HC1) ? W1l[k * HC1 + col] : W1r[k * HC1 + (col - HC1)];
  int boff = (col * 1024 + k * 2) ^ ((col & 7) << 4);
  Wimg[boff >> 1] = (_Float16)v;
}

// ---------------- GEMM1: fp16 2-product MFMA, weight-stationary in LDS -------
// 256 blocks (1/CU), 512 threads (8 waves). LDS: W table 128KB + A 16KB hi
// + 16KB lo (scaled x2048) = 160KiB exactly. Waves: colgrp = wid&3 owns 32
// cols, khalf = wid>>2 owns 8 of 16 K-windows; split-K partials combined via
// LDS. Grid-strides over 6250 M=16 tiles, reg-prefetching next tile's x.
#define B_LDS_BYTES 131072
#define ABASE 131072
#define ALO   16384

__global__ __launch_bounds__(512, 1) void k_gemm1(const float* __restrict__ x,
    const uint4* __restrict__ Wimg, float* __restrict__ xl, float* __restrict__ xr) {
  __shared__ char lds[163840];
  const int tid  = threadIdx.x;
  const int lane = tid & 63, wid = tid >> 6;
  const int lrow = lane & 15, kg = lane >> 4;
  const int colgrp = wid & 3;
  const int kw0 = (wid >> 2) * 8;

  // ---- copy W image (L2/L3-hot) into LDS, linear
#pragma unroll
  for (int i = 0; i < 16; ++i) {
    int idx = i * 512 + tid;
    uint4 v = Wimg[idx];
    *(uint4*)(lds + idx * 16) = v;
  }

  // ---- per-thread staging map (constant across tiles)
  int xoff[4], aoff[4], mode[4];   // mode: 0=data, 1=pad, 2=none
#pragma unroll
  for (int i = 0; i < 4; ++i) {
    int s = tid + i * 512;
    if (s < 2000) {
      int row = s / 125, c4 = s - row * 125;
      xoff[i] = row * 500 + c4 * 4;
      aoff[i] = (row * 1024 + c4 * 8) ^ ((row & 7) << 4);
      mode[i] = 0;
    } else {
      int p = s - 2000;           // 0..47
      int row = p / 3, j = p - row * 3;
      aoff[i] = (row * 1024 + 1000 + j * 8) ^ ((row & 7) << 4);
      xoff[i] = 0;
      mode[i] = 1;
    }
  }

  float4 rv[4];
  auto loadregs = [&](int tile) {
#pragma unroll
    for (int i = 0; i < 4; ++i)
      if (mode[i] == 0)
        rv[i] = *(const float4*)&x[(size_t)tile * 8000 + xoff[i]];
  };

  loadregs(blockIdx.x);
  __syncthreads();   // W table resident

  for (int tile = blockIdx.x; tile < TILES; tile += NBLK) {
    // ---- stage A: convert fp32 regs -> fp16 hi + (lo * 2048), swizzled LDS
#pragma unroll
    for (int i = 0; i < 4; ++i) {
      f16x4 h, l;
      if (mode[i] == 0) {
        float vals[4] = {rv[i].x, rv[i].y, rv[i].z, rv[i].w};
#pragma unroll
        for (int c = 0; c < 4; ++c) {
          _Float16 hh = (_Float16)vals[c];
          float r = vals[c] - (float)hh;
          h[c] = hh;
          l[c] = (_Float16)(r * 2048.f);
        }
      } else {
        h = (f16x4){0, 0, 0, 0}; l = (f16x4){0, 0, 0, 0};
      }
      *(f16x4*)(lds + ABASE + aoff[i]) = h;
      *(f16x4*)(lds + ABASE + ALO + aoff[i]) = l;
    }
    __syncthreads();   // A(t) visible
    if (tile + NBLK < TILES) loadregs(tile + NBLK);   // prefetch under compute

    // ---- compute: 8 K-windows x {2 A-frags, 2 B-frags, 4 MFMA}
    f32x4 acch[2], accl[2];
    acch[0] = (f32x4){0,0,0,0}; acch[1] = (f32x4){0,0,0,0};
    accl[0] = (f32x4){0,0,0,0}; accl[1] = (f32x4){0,0,0,0};
#pragma unroll
    for (int kw = 0; kw < 8; ++kw) {
      const int kwin = kw0 + kw;
      const int koff = kwin * 64 + kg * 16;
      int ao = (lrow * 1024 + koff) ^ ((lrow & 7) << 4);
      f16x8 ah = *(const f16x8*)(lds + ABASE + ao);
      f16x8 al = *(const f16x8*)(lds + ABASE + ALO + ao);
#pragma unroll
      for (int n = 0; n < 2; ++n) {
        int col = colgrp * 32 + n * 16 + lrow;
        int bo = (col * 1024 + koff) ^ ((col & 7) << 4);
        f16x8 b = *(const f16x8*)(lds + bo);
        acch[n] = __builtin_amdgcn_mfma_f32_16x16x32_f16(ah, b, acch[n], 0, 0, 0);
        accl[n] = __builtin_amdgcn_mfma_f32_16x16x32_f16(al, b, accl[n], 0, 0, 0);
      }
    }
    // ---- epilogue: v = acc_h + acc_l/2048; split-K combine via LDS
    float v[2][4];
#pragma unroll
    for (int n = 0; n < 2; ++n)
#pragma unroll
      for (int j = 0; j < 4; ++j)
        v[n][j] = acch[n][j] + accl[n][j] * 4.8828125e-4f;

    if (wid >= 4) {   // upper K-half: publish partials into A region (dead)
      char* p = lds + ABASE + ((wid - 4) * 64 + lane) * 32;
      *(float4*)p       = make_float4(v[0][0], v[0][1], v[0][2], v[0][3]);
      *(float4*)(p+16)  = make_float4(v[1][0], v[1][1], v[1][2], v[1][3]);
    }
    __syncthreads();
    if (wid < 4) {    // lower K-half: combine + store C
      const char* p = lds + ABASE + (wid * 64 + lane) * 32;
      float4 p0 = *(const float4*)p, p1 = *(const float4*)(p+16);
      v[0][0]+=p0.x; v[0][1]+=p0.y; v[0][2]+=p0.z; v[0][3]+=p0.w;
      v[1][0]+=p1.x; v[1][1]+=p1.y; v[1][2]+=p1.z; v[1][3]+=p1.w;
      float* dst = (colgrp < 2) ? xl : xr;
      const int bm0 = tile * 16;
#pragma unroll
      for (int n = 0; n < 2; ++n) {
        int cc = (colgrp * 32 + n * 16 + lrow) & 63;
#pragma unroll
        for (int j = 0; j < 4; ++j)
          dst[(size_t)(bm0 + kg * 4 + j) * HC1 + cc] = v[n][j];
      }
    }
    __syncthreads();  // partials consumed; A region free for next stage
  }
}

// ---------------- layer-1 edge pass: online segment softmax + aggregate ------
// thread = (node, head); 8 consecutive lanes = 8 heads of one node.
// 2-way edge unroll: two independent row gathers in flight.
__global__ __launch_bounds__(256) void k_edge1(const float* __restrict__ xl1,
    const float* __restrict__ xr1, const float* __restrict__ att1,
    const float* __restrict__ b1, const int* __restrict__ rowptr,
    const int* __restrict__ esrc, float* __restrict__ hbuf) {
  int t = blockIdx.x * blockDim.x + threadIdx.x;   // exact grid: N*8
  int node = t >> 3, h = t & 7;
  const float4* xrp = (const float4*)(xr1 + (size_t)node * HC1 + h * C1);
  float4 xa = xrp[0], xb = xrp[1];
  float xrv[8] = {xa.x, xa.y, xa.z, xa.w, xb.x, xb.y, xb.z, xb.w};
  const float4* ap = (const float4*)(att1 + h * C1);
  float4 aa = ap[0], ab = ap[1];
  float av[8] = {aa.x, aa.y, aa.z, aa.w, ab.x, ab.y, ab.z, ab.w};

  float m = -INFINITY, s = 0.f;
  float acc[8];
#pragma unroll
  for (int c = 0; c < 8; ++c) acc[c] = 0.f;

  auto gather = [&](int sn, float* v) {
    const float4* p = (const float4*)(xl1 + (size_t)sn * HC1 + h * C1);
    float4 A = p[0], B = p[1];
    v[0]=A.x; v[1]=A.y; v[2]=A.z; v[3]=A.w; v[4]=B.x; v[5]=B.y; v[6]=B.z; v[7]=B.w;
  };
  auto process = [&](const float* v) {
    float logit = 0.f;
#pragma unroll
    for (int c = 0; c < 8; ++c) {
      float u = v[c] + xrv[c];
      u = (u > 0.f) ? u : NEG * u;
      logit = fmaf(u, av[c], logit);
    }
    float mn = fmaxf(m, logit);
    float so = __expf(m - mn);
    float p  = __expf(logit - mn);
    s = s * so + p;
#pragma unroll
    for (int c = 0; c < 8; ++c) acc[c] = fmaf(acc[c], so, p * v[c]);
    m = mn;
  };

  int beg = rowptr[node], end = rowptr[node + 1];
  int i = beg;
  for (; i + 1 < end; i += 2) {
    int sn0 = esrc[i], sn1 = esrc[i + 1];
    float v0[8], v1[8];
    gather(sn0, v0); gather(sn1, v1);
    process(v0); process(v1);
  }
  if (i < end) { float v0[8]; gather(esrc[i], v0); process(v0); }

  float inv = 1.f / s;
  float o[8];
#pragma unroll
  for (int c = 0; c < 8; ++c) {
    float v = fmaf(acc[c], inv, b1[h * C1 + c]);
    o[c] = (v > 0.f) ? v : expm1f(v);    // ELU
  }
  float4* hp = (float4*)(hbuf + (size_t)node * HC1 + h * C1);
  hp[0] = make_float4(o[0], o[1], o[2], o[3]);
  hp[1] = make_float4(o[4], o[5], o[6], o[7]);
}

// ---------------- GEMM2: xl2 = h@W2l, xr2 = h@W2r  (64 -> 24 each) -----------
__global__ __launch_bounds__(256) void k_gemm2(const float* __restrict__ hbuf,
    const float* __restrict__ W2l, const float* __restrict__ W2r,
    float* __restrict__ xl2, float* __restrict__ xr2) {
  __shared__ float w[64][48];
  int tid = threadIdx.x;
  for (int i = tid; i < 64 * 48; i += 256) {
    int k = i / 48, j = i - k * 48;
    w[k][j] = (j < HC2) ? W2l[k * HC2 + j] : W2r[k * HC2 + (j - HC2)];
  }
  __syncthreads();
  int node = blockIdx.x * 256 + tid;
  if (node >= N_NODES) return;
  float acc[48];
#pragma unroll
  for (int j = 0; j < 48; ++j) acc[j] = 0.f;
  const float4* hp = (const float4*)(hbuf + (size_t)node * HC1);
  for (int k0 = 0; k0 < 64; k0 += 16) {
    float rv[16];
#pragma unroll
    for (int q = 0; q < 4; ++q) {
      float4 r4 = hp[k0 / 4 + q];
      rv[q*4+0] = r4.x; rv[q*4+1] = r4.y; rv[q*4+2] = r4.z; rv[q*4+3] = r4.w;
    }
#pragma unroll
    for (int kk = 0; kk < 16; ++kk) {
      float hv = rv[kk];
      const float4* wrow = (const float4*)&w[k0 + kk][0];
#pragma unroll
      for (int j4 = 0; j4 < 12; ++j4) {
        float4 wv = wrow[j4];
        acc[j4*4+0] = fmaf(hv, wv.x, acc[j4*4+0]);
        acc[j4*4+1] = fmaf(hv, wv.y, acc[j4*4+1]);
        acc[j4*4+2] = fmaf(hv, wv.z, acc[j4*4+2]);
        acc[j4*4+3] = fmaf(hv, wv.w, acc[j4*4+3]);
      }
    }
  }
  float4* lp = (float4*)(xl2 + (size_t)node * HC2);
  float4* rp = (float4*)(xr2 + (size_t)node * HC2);
#pragma unroll
  for (int j4 = 0; j4 < 6; ++j4) {
    lp[j4] = make_float4(acc[j4*4+0], acc[j4*4+1], acc[j4*4+2], acc[j4*4+3]);
    rp[j4] = make_float4(acc[24+j4*4+0], acc[24+j4*4+1], acc[24+j4*4+2], acc[24+j4*4+3]);
  }
}

// ---------------- layer-2 edge pass + head-mean + final softmax --------------
__global__ __launch_bounds__(256) void k_edge2(const float* __restrict__ xl2,
    const float* __restrict__ xr2, const float* __restrict__ att2,
    const float* __restrict__ b2, const int* __restrict__ rowptr,
    const int* __restrict__ esrc, float* __restrict__ out) {
  int t = blockIdx.x * blockDim.x + threadIdx.x;   // exact grid: N*8
  int node = t >> 3, h = t & 7;
  float xrv[3], av[3];
#pragma unroll
  for (int c = 0; c < 3; ++c) {
    xrv[c] = xr2[(size_t)node * HC2 + h * NCLS + c];
    av[c]  = att2[h * NCLS + c];
  }
  float m = -INFINITY, s = 0.f;
  float acc[3] = {0.f, 0.f, 0.f};

  auto process = [&](const float* v) {
    float logit = 0.f;
#pragma unroll
    for (int c = 0; c < 3; ++c) {
      float u = v[c] + xrv[c];
      u = (u > 0.f) ? u : NEG * u;
      logit = fmaf(u, av[c], logit);
    }
    float mn = fmaxf(m, logit);
    float so = __expf(m - mn);
    float p  = __expf(logit - mn);
    s = s * so + p;
#pragma unroll
    for (int c = 0; c < 3; ++c) acc[c] = fmaf(acc[c], so, p * v[c]);
    m = mn;
  };

  int beg = rowptr[node], end = rowptr[node + 1];
  int i = beg;
  for (; i + 1 < end; i += 2) {
    int sn0 = esrc[i], sn1 = esrc[i + 1];
    float v0[3], v1[3];
#pragma unroll
    for (int c = 0; c < 3; ++c) v0[c] = xl2[(size_t)sn0 * HC2 + h * NCLS + c];
#pragma unroll
    for (int c = 0; c < 3; ++c) v1[c] = xl2[(size_t)sn1 * HC2 + h * NCLS + c];
    process(v0); process(v1);
  }
  if (i < end) {
    int sn0 = esrc[i];
    float v0[3];
#pragma unroll
    for (int c = 0; c < 3; ++c) v0[c] = xl2[(size_t)sn0 * HC2 + h * NCLS + c];
    process(v0);
  }

  float inv = 1.f / s;
  float o[3];
#pragma unroll
  for (int c = 0; c < 3; ++c) o[c] = acc[c] * inv;
  // mean over 8 heads (8-lane group butterfly; grid exact so all lanes live)
#pragma unroll
  for (int off = 1; off < 8; off <<= 1) {
#pragma unroll
    for (int c = 0; c < 3; ++c) o[c] += __shfl_xor(o[c], off);
  }
  if (h < 3) {
    float z[3];
#pragma unroll
    for (int c = 0; c < 3; ++c) z[c] = o[c] * 0.125f + b2[c];
    float mx = fmaxf(fmaxf(z[0], z[1]), z[2]);
    float e0 = __expf(z[0] - mx), e1 = __expf(z[1] - mx), e2 = __expf(z[2] - mx);
    float sum = e0 + e1 + e2;
    float num = (h == 0) ? e0 : (h == 1) ? e1 : e2;
    out[(size_t)node * NCLS + h] = num / sum;
  }
}

// ---------------- launch -----------------------------------------------------
extern "C" void kernel_launch(void* const* d_in, const int* in_sizes, int n_in,
                              void* d_out, int out_size, void* d_ws, size_t ws_size,
                              hipStream_t stream) {
  (void)in_sizes; (void)n_in; (void)out_size; (void)ws_size;
  const float* x    = (const float*)d_in[0];
  const int*   ei   = (const int*)d_in[1];
  const float* W1l  = (const float*)d_in[2];
  const float* W1r  = (const float*)d_in[3];
  const float* att1 = (const float*)d_in[4];
  const float* b1   = (const float*)d_in[5];
  const float* W2l  = (const float*)d_in[6];
  const float* W2r  = (const float*)d_in[7];
  const float* att2 = (const float*)d_in[8];
  const float* b2   = (const float*)d_in[9];
  float* out = (float*)d_out;

  char* w = (char*)d_ws;
  float* xl1  = (float*)(w);                 // 25.6 MB
  float* xr1  = (float*)(w + 25600000);      // 25.6 MB
  float* hbuf = (float*)(w + 51200000);      // 25.6 MB (W image lives here pre-edge1)
  float* xl2  = (float*)(w);                 // overlays xl1 (dead after edge1)
  float* xr2  = (float*)(w + 9600000);       // inside old xl1 region
  _Float16* Wimg = (_Float16*)(w + 51200000);          // 128 KB fp16 LDS-image
  char* ip = w + 76800000;
  int* deg    = (int*)(ip);                  // 400000 B
  int* cnt    = (int*)(ip + 400000);         // 400000 B
  int* rowptr = (int*)(ip + 800000);         // 400004 B
  int* segsum = (int*)(ip + 1200256);
  int* segoff = (int*)(ip + 1200512);
  int* flag   = (int*)(ip + 1200768);
  int* esrc   = (int*)(ip + 1201024);        // 6.8 MB  -> total ~84.8 MB

  hipMemsetAsync(deg, 0, 800000, stream);    // deg + cnt (contiguous)
  hipMemsetAsync(flag, 0, 4, stream);

  k_detect   <<<16, 256, 0, stream>>>(ei, flag);
  k_wconv    <<<256, 256, 0, stream>>>(W1l, W1r, Wimg);
  k_hist     <<<(E_TOT + 255) / 256, 256, 0, stream>>>(ei, flag, deg);
  k_seg_sum  <<<NSEG, 256, 0, stream>>>(deg, segsum);
  k_scan_small<<<1, 64, 0, stream>>>(segsum, segoff, rowptr);
  k_seg_scan <<<NSEG, 256, 0, stream>>>(deg, segoff, rowptr);
  k_scatter  <<<(E_TOT + 255) / 256, 256, 0, stream>>>(ei, flag, rowptr, cnt, esrc);
  k_gemm1    <<<NBLK, 512, 0, stream>>>(x, (const uint4*)Wimg, xl1, xr1);
  k_edge1    <<<(N_NODES * HEADS) / 256, 256, 0, stream>>>(xl1, xr1, att1, b1, rowptr, esrc, hbuf);
  k_gemm2    <<<(N_NODES + 255) / 256, 256, 0, stream>>>(hbuf, W2l, W2r, xl2, xr2);
  k_edge2    <<<N_NODES * HEADS / 256, 256, 0, stream>>>(xl2, xr2, att2, b2, rowptr, esrc, out);
}